// Round 4
// baseline (434.683 us; speedup 1.0000x reference)
//
#include <hip/hip_runtime.h>
#include <hip/hip_bf16.h>

#define N_NODES 10000
#define N_EDGES 160000
#define F_IN    128
#define F_OUT   128
#define BATCH   8

// ---------------- workspace layout (bytes) ----------------
#define WS_FLAG_OFF   0
#define WS_WT_OFF     256
#define WS_DEG_OFF    131328
#define WS_ROW_OFF    171328
#define WS_CUR_OFF    211332
#define WS_COL_OFF    251332
#define WS_TOTAL      891332

__device__ __forceinline__ int edge_val(const void* ei, int idx, int i64) {
    if (i64) return (int)((const long long*)ei)[idx];
    return ((const int*)ei)[idx];
}

// Detect whether edge_index arrived as int64 (odd 32-bit words of first 256
// entries all zero) or int32. Values are < 10000 so int64 high words are 0.
__global__ void detect_i64_kernel(const void* ei, int* flag) {
    __shared__ int any_nonzero;
    if (threadIdx.x == 0) any_nonzero = 0;
    __syncthreads();
    int v = ((const int*)ei)[2 * threadIdx.x + 1];
    if (v != 0) atomicOr(&any_nonzero, 1);
    __syncthreads();
    if (threadIdx.x == 0) *flag = (any_nonzero == 0) ? 1 : 0;
}

// Wcat_t[f][o] = (f<128 ? W_l[o][f] : W_r[o][f-128])
__global__ void transpose_w_kernel(const float* __restrict__ Wl,
                                   const float* __restrict__ Wr,
                                   float* __restrict__ Wt) {
    int idx = blockIdx.x * 256 + threadIdx.x;   // 0 .. 256*128-1
    int f = idx >> 7;
    int o = idx & 127;
    float v = (f < F_IN) ? Wl[o * F_IN + f] : Wr[o * F_IN + (f - F_IN)];
    Wt[f * F_OUT + o] = v;
}

__global__ void hist_kernel(const void* ei, const int* __restrict__ flag,
                            int* __restrict__ deg) {
    int e = blockIdx.x * 256 + threadIdx.x;
    if (e >= N_EDGES) return;
    int i64 = *flag;
    int d = edge_val(ei, N_EDGES + e, i64);
    atomicAdd(&deg[d], 1);
}

__global__ __launch_bounds__(1024)
void scan_kernel(const int* __restrict__ deg, int* __restrict__ row_start) {
    __shared__ int sd[1024];
    const int CH = (N_NODES + 1023) / 1024;   // 10
    int t = threadIdx.x;
    int beg = t * CH;
    int end = min(N_NODES, beg + CH);
    int s = 0;
    for (int i = beg; i < end; i++) s += deg[i];
    sd[t] = s;
    __syncthreads();
    for (int off = 1; off < 1024; off <<= 1) {
        int v = (t >= off) ? sd[t - off] : 0;
        __syncthreads();
        sd[t] += v;
        __syncthreads();
    }
    int run = sd[t] - s;   // exclusive prefix
    for (int i = beg; i < end; i++) { row_start[i] = run; run += deg[i]; }
    if (t == 1023) row_start[N_NODES] = sd[1023];
}

__global__ void scatter_kernel(const void* ei, const int* __restrict__ flag,
                               const int* __restrict__ row_start,
                               int* __restrict__ cursor, int* __restrict__ col) {
    int e = blockIdx.x * 256 + threadIdx.x;
    if (e >= N_EDGES) return;
    int i64 = *flag;
    int s = edge_val(ei, e, i64);
    int d = edge_val(ei, N_EDGES + e, i64);
    int pos = atomicAdd(&cursor[d], 1);
    col[row_start[d] + pos] = s;
}

// One block per node. 256 threads = 8 batches x 32 float4 chunks.
// Phase A: gather-accumulate neighbor features into registers, write
//          [mean ; x_self] (8 x 256 f32) into LDS.
// Phase B: each thread computes 4 outputs for its batch via Wcat_t.
__global__ __launch_bounds__(256)
void sage_fused_kernel(const float* __restrict__ x,
                       const float* __restrict__ bl,
                       const float* __restrict__ Wt,
                       const int* __restrict__ row_start,
                       const int* __restrict__ col,
                       float* __restrict__ out) {
    __shared__ float in_lds[BATCH][2 * F_IN];   // 8 KB

    const int n = blockIdx.x;
    const int t = threadIdx.x;
    const int b = t >> 5;        // batch 0..7
    const int c = t & 31;        // float4 chunk 0..31 (covers 128 floats)

    const int beg = row_start[n];
    const int end = row_start[n + 1];

    const float* xb = x + (size_t)b * N_NODES * F_IN;

    float4 acc = make_float4(0.f, 0.f, 0.f, 0.f);
    for (int i = beg; i < end; i++) {
        int s = col[i];
        const float4 v = *(const float4*)(xb + (size_t)s * F_IN + c * 4);
        acc.x += v.x; acc.y += v.y; acc.z += v.z; acc.w += v.w;
    }
    const float inv = 1.0f / (float)max(end - beg, 1);
    const float4 self = *(const float4*)(xb + (size_t)n * F_IN + c * 4);

    *(float4*)&in_lds[b][c * 4] =
        make_float4(acc.x * inv, acc.y * inv, acc.z * inv, acc.w * inv);
    *(float4*)&in_lds[b][F_IN + c * 4] = self;
    __syncthreads();

    // Phase B: outputs o = c*4 .. c*4+3 for batch b
    float4 oacc = *(const float4*)(bl + c * 4);
    #pragma unroll 8
    for (int f4 = 0; f4 < 64; f4++) {
        const float4 inq = *(const float4*)&in_lds[b][f4 * 4];
        const float4 w0 = *(const float4*)(Wt + (f4 * 4 + 0) * F_OUT + c * 4);
        const float4 w1 = *(const float4*)(Wt + (f4 * 4 + 1) * F_OUT + c * 4);
        const float4 w2 = *(const float4*)(Wt + (f4 * 4 + 2) * F_OUT + c * 4);
        const float4 w3 = *(const float4*)(Wt + (f4 * 4 + 3) * F_OUT + c * 4);
        oacc.x += inq.x * w0.x; oacc.y += inq.x * w0.y; oacc.z += inq.x * w0.z; oacc.w += inq.x * w0.w;
        oacc.x += inq.y * w1.x; oacc.y += inq.y * w1.y; oacc.z += inq.y * w1.z; oacc.w += inq.y * w1.w;
        oacc.x += inq.z * w2.x; oacc.y += inq.z * w2.y; oacc.z += inq.z * w2.z; oacc.w += inq.z * w2.w;
        oacc.x += inq.w * w3.x; oacc.y += inq.w * w3.y; oacc.z += inq.w * w3.z; oacc.w += inq.w * w3.w;
    }

    *(float4*)(out + ((size_t)b * N_NODES + n) * F_OUT + c * 4) = oacc;
}

extern "C" void kernel_launch(void* const* d_in, const int* in_sizes, int n_in,
                              void* d_out, int out_size, void* d_ws, size_t ws_size,
                              hipStream_t stream) {
    const float* x  = (const float*)d_in[0];
    const float* Wl = (const float*)d_in[1];
    const float* bl = (const float*)d_in[2];
    const float* Wr = (const float*)d_in[3];
    const void*  ei = d_in[4];

    char* ws = (char*)d_ws;
    int*   flag      = (int*)(ws + WS_FLAG_OFF);
    float* Wt        = (float*)(ws + WS_WT_OFF);
    int*   deg       = (int*)(ws + WS_DEG_OFF);
    int*   row_start = (int*)(ws + WS_ROW_OFF);
    int*   cursor    = (int*)(ws + WS_CUR_OFF);
    int*   col       = (int*)(ws + WS_COL_OFF);

    float* out = (float*)d_out;

    hipMemsetAsync(d_ws, 0, WS_TOTAL, stream);
    detect_i64_kernel<<<1, 256, 0, stream>>>(ei, flag);
    transpose_w_kernel<<<(256 * 128) / 256, 256, 0, stream>>>(Wl, Wr, Wt);
    hist_kernel<<<(N_EDGES + 255) / 256, 256, 0, stream>>>(ei, flag, deg);
    scan_kernel<<<1, 1024, 0, stream>>>(deg, row_start);
    scatter_kernel<<<(N_EDGES + 255) / 256, 256, 0, stream>>>(ei, flag, row_start, cursor, col);
    sage_fused_kernel<<<N_NODES, 256, 0, stream>>>(x, bl, Wt, row_start, col, out);
}

// Round 8
// 221.322 us; speedup vs baseline: 1.9640x; 1.9640x over previous
//
#include <hip/hip_runtime.h>
#include <hip/hip_bf16.h>

#define N_NODES 10000
#define N_EDGES 160000
#define F_IN    128
#define F_OUT   128
#define BATCH   8
#define NROWS   (BATCH * N_NODES)   // 80000

// ---------------- OLD (fallback) workspace layout ----------------
#define WS_FLAG_OFF   0
#define WS_WT_OFF     256
#define WS_DEG_OFF    131328
#define WS_ROW_OFF    171328
#define WS_CUR_OFF    211332
#define WS_COL_OFF    251332
#define WS_TOTAL      891332

// ---------------- NEW bf16 workspace layout ----------------
#define WS2_FLAG  0
#define WS2_WT    256          // bf16 Wcat [128][256] = 65536
#define WS2_DEG   65792       // 40000
#define WS2_ROW   105792      // 40004
#define WS2_CUR   145796      // 40000
#define WS2_COL   185796      // 640000
#define WS2_XH    825856      // 8*10000*128*2 = 20480000
#define WS2_Z     21305856    // 8*10000*256*2 = 40960000
#define WS2_TOTAL 62265856

typedef __attribute__((ext_vector_type(8))) short short8;
typedef __attribute__((ext_vector_type(4))) float floatx4;

__device__ __forceinline__ int edge_val(const void* ei, int idx, int i64) {
    if (i64) return (int)((const long long*)ei)[idx];
    return ((const int*)ei)[idx];
}

__global__ void detect_i64_kernel(const void* ei, int* flag) {
    __shared__ int any_nonzero;
    if (threadIdx.x == 0) any_nonzero = 0;
    __syncthreads();
    int v = ((const int*)ei)[2 * threadIdx.x + 1];
    if (v != 0) atomicOr(&any_nonzero, 1);
    __syncthreads();
    if (threadIdx.x == 0) *flag = (any_nonzero == 0) ? 1 : 0;
}

__global__ void hist_kernel(const void* ei, const int* __restrict__ flag,
                            int* __restrict__ deg) {
    int e = blockIdx.x * 256 + threadIdx.x;
    if (e >= N_EDGES) return;
    int i64 = *flag;
    int d = edge_val(ei, N_EDGES + e, i64);
    atomicAdd(&deg[d], 1);
}

__global__ __launch_bounds__(1024)
void scan_kernel(const int* __restrict__ deg, int* __restrict__ row_start) {
    __shared__ int sd[1024];
    const int CH = (N_NODES + 1023) / 1024;   // 10
    int t = threadIdx.x;
    int beg = t * CH;
    int end = min(N_NODES, beg + CH);
    int s = 0;
    for (int i = beg; i < end; i++) s += deg[i];
    sd[t] = s;
    __syncthreads();
    for (int off = 1; off < 1024; off <<= 1) {
        int v = (t >= off) ? sd[t - off] : 0;
        __syncthreads();
        sd[t] += v;
        __syncthreads();
    }
    int run = sd[t] - s;   // exclusive prefix
    for (int i = beg; i < end; i++) { row_start[i] = run; run += deg[i]; }
    if (t == 1023) row_start[N_NODES] = sd[1023];
}

__global__ void scatter_kernel(const void* ei, const int* __restrict__ flag,
                               const int* __restrict__ row_start,
                               int* __restrict__ cursor, int* __restrict__ col) {
    int e = blockIdx.x * 256 + threadIdx.x;
    if (e >= N_EDGES) return;
    int i64 = *flag;
    int s = edge_val(ei, e, i64);
    int d = edge_val(ei, N_EDGES + e, i64);
    int pos = atomicAdd(&cursor[d], 1);
    col[row_start[d] + pos] = s;
}

// ======================= NEW bf16 path =======================

__device__ __forceinline__ unsigned short f2bf(float v) {
    __hip_bfloat16 h = __float2bfloat16(v);
    return *(unsigned short*)&h;
}

__device__ __forceinline__ uint2 pack4(float4 v) {
    uint2 r;
    r.x = (unsigned)f2bf(v.x) | ((unsigned)f2bf(v.y) << 16);
    r.y = (unsigned)f2bf(v.z) | ((unsigned)f2bf(v.w) << 16);
    return r;
}

__device__ __forceinline__ void acc4(float4& a, uint2 p) {
    a.x += __uint_as_float(p.x << 16);
    a.y += __uint_as_float(p.x & 0xffff0000u);
    a.z += __uint_as_float(p.y << 16);
    a.w += __uint_as_float(p.y & 0xffff0000u);
}

// Wcat_bf16[o][k]: k<128 -> W_l[o][k], else W_r[o][k-128]
__global__ void make_wt_bf16(const float* __restrict__ Wl,
                             const float* __restrict__ Wr,
                             unsigned short* __restrict__ Wt) {
    int idx = blockIdx.x * 256 + threadIdx.x;   // 0..32767
    int o = idx >> 8;
    int k = idx & 255;
    float v = (k < F_IN) ? Wl[o * F_IN + k] : Wr[o * F_IN + (k - F_IN)];
    Wt[idx] = f2bf(v);
}

// x (fp32) -> xh (bf16) and self half of z
__global__ __launch_bounds__(256)
void convert_kernel(const float* __restrict__ x,
                    uint2* __restrict__ xh2, uint2* __restrict__ z2) {
    int t = blockIdx.x * 256 + threadIdx.x;     // 0..2559999 (row*32+c)
    float4 v = ((const float4*)x)[t];
    uint2 p = pack4(v);
    xh2[t] = p;
    int row = t >> 5, c = t & 31;
    z2[(size_t)row * 64 + 32 + c] = p;
}

// one block per node; 256 threads = 8 batches x 32 uint2-chunks (8B each)
__global__ __launch_bounds__(256)
void gather_bf16_kernel(const uint2* __restrict__ xh2,
                        const int* __restrict__ row_start,
                        const int* __restrict__ col,
                        uint2* __restrict__ z2) {
    __shared__ int nbr[1024];
    const int n = blockIdx.x;
    const int t = threadIdx.x;
    const int b = t >> 5;
    const int c = t & 31;

    const int beg = row_start[n];
    const int end = row_start[n + 1];
    const int d   = end - beg;
    const int cnt = min(d, 1024);

    for (int i = t; i < cnt; i += 256) nbr[i] = col[beg + i];
    __syncthreads();

    const size_t bbase = (size_t)b * N_NODES;

    float4 s0 = make_float4(0,0,0,0), s1 = s0, s2 = s0, s3 = s0;
    int i = 0;
    for (; i + 4 <= cnt; i += 4) {
        int n0 = nbr[i], n1 = nbr[i+1], n2 = nbr[i+2], n3 = nbr[i+3];
        uint2 v0 = xh2[(bbase + n0) * 32 + c];
        uint2 v1 = xh2[(bbase + n1) * 32 + c];
        uint2 v2 = xh2[(bbase + n2) * 32 + c];
        uint2 v3 = xh2[(bbase + n3) * 32 + c];
        acc4(s0, v0); acc4(s1, v1); acc4(s2, v2); acc4(s3, v3);
    }
    for (; i < cnt; i++) {
        uint2 v = xh2[(bbase + nbr[i]) * 32 + c];
        acc4(s0, v);
    }
    for (int j = 1024; j < d; j++) {   // pathological-degree fallback
        uint2 v = xh2[(bbase + col[beg + j]) * 32 + c];
        acc4(s0, v);
    }
    s0.x += s1.x + s2.x + s3.x; s0.y += s1.y + s2.y + s3.y;
    s0.z += s1.z + s2.z + s3.z; s0.w += s1.w + s2.w + s3.w;
    const float inv = 1.0f / (float)max(d, 1);
    float4 m = make_float4(s0.x*inv, s0.y*inv, s0.z*inv, s0.w*inv);
    z2[((bbase + n)) * 64 + c] = pack4(m);
}

// out[m][o] = sum_k z[m][k] * Wt[o][k] + bl[o]; M=80000, K=256, N=128
// BM=64 tile, 4 waves each own 16 rows; XOR-swizzled LDS A-tile.
__global__ __launch_bounds__(256)
void gemm_bf16_kernel(const unsigned short* __restrict__ z,
                      const unsigned short* __restrict__ Wt,
                      const float* __restrict__ bl,
                      float* __restrict__ out) {
    __shared__ unsigned short A[64 * 256];   // 32 KB

    const int tid = threadIdx.x;
    const int m0 = blockIdx.x * 64;

    // stage 64 rows x 512 B with write-side XOR swizzle (chunk ^= row&7)
    #pragma unroll
    for (int it = 0; it < 8; ++it) {
        int byte = it * 4096 + tid * 16;
        int r = byte >> 9;            // 0..63
        int cch = (byte >> 4) & 31;   // 16B chunk in row
        uint4 v = *(const uint4*)(z + (size_t)(m0 + r) * 256 + cch * 8);
        int dch = cch ^ (r & 7);
        *(uint4*)((char*)A + r * 512 + dch * 16) = v;
    }
    __syncthreads();

    const int w  = tid >> 6;   // wave 0..3
    const int l  = tid & 63;
    const int lr = l & 15;
    const int kg = l >> 4;     // 0..3

    floatx4 acc[8];
    #pragma unroll
    for (int j = 0; j < 8; ++j) acc[j] = (floatx4){0.f, 0.f, 0.f, 0.f};

    #pragma unroll
    for (int ks = 0; ks < 8; ++ks) {
        const int r = w * 16 + lr;
        const int cch = ks * 4 + kg;               // chunk = k0/8
        short8 af = *(const short8*)((const char*)A + r * 512 + ((cch ^ (r & 7)) * 16));
        #pragma unroll
        for (int jt = 0; jt < 8; ++jt) {
            short8 bf = *(const short8*)(Wt + (size_t)(jt * 16 + lr) * 256 + ks * 32 + kg * 8);
            acc[jt] = __builtin_amdgcn_mfma_f32_16x16x32_bf16(af, bf, acc[jt], 0, 0, 0);
        }
    }

    #pragma unroll
    for (int jt = 0; jt < 8; ++jt) {
        const int colo = jt * 16 + lr;
        const float bias = bl[colo];
        const int rbase = m0 + w * 16 + kg * 4;
        #pragma unroll
        for (int q = 0; q < 4; ++q) {
            out[(size_t)(rbase + q) * F_OUT + colo] = acc[jt][q] + bias;
        }
    }
}

// ======================= OLD fp32 fallback path =======================

__global__ void transpose_w_kernel(const float* __restrict__ Wl,
                                   const float* __restrict__ Wr,
                                   float* __restrict__ Wt) {
    int idx = blockIdx.x * 256 + threadIdx.x;
    int f = idx >> 7;
    int o = idx & 127;
    float v = (f < F_IN) ? Wl[o * F_IN + f] : Wr[o * F_IN + (f - F_IN)];
    Wt[f * F_OUT + o] = v;
}

__global__ __launch_bounds__(256)
void sage_fused_kernel(const float* __restrict__ x,
                       const float* __restrict__ bl,
                       const float* __restrict__ Wt,
                       const int* __restrict__ row_start,
                       const int* __restrict__ col,
                       float* __restrict__ out) {
    __shared__ float in_lds[BATCH][2 * F_IN];

    const int n = blockIdx.x;
    const int t = threadIdx.x;
    const int b = t >> 5;
    const int c = t & 31;

    const int beg = row_start[n];
    const int end = row_start[n + 1];

    const float* xb = x + (size_t)b * N_NODES * F_IN;

    float4 acc = make_float4(0.f, 0.f, 0.f, 0.f);
    for (int i = beg; i < end; i++) {
        int s = col[i];
        const float4 v = *(const float4*)(xb + (size_t)s * F_IN + c * 4);
        acc.x += v.x; acc.y += v.y; acc.z += v.z; acc.w += v.w;
    }
    const float inv = 1.0f / (float)max(end - beg, 1);
    const float4 self = *(const float4*)(xb + (size_t)n * F_IN + c * 4);

    *(float4*)&in_lds[b][c * 4] =
        make_float4(acc.x * inv, acc.y * inv, acc.z * inv, acc.w * inv);
    *(float4*)&in_lds[b][F_IN + c * 4] = self;
    __syncthreads();

    float4 oacc = *(const float4*)(bl + c * 4);
    #pragma unroll 8
    for (int f4 = 0; f4 < 64; f4++) {
        const float4 inq = *(const float4*)&in_lds[b][f4 * 4];
        const float4 w0 = *(const float4*)(Wt + (f4 * 4 + 0) * F_OUT + c * 4);
        const float4 w1 = *(const float4*)(Wt + (f4 * 4 + 1) * F_OUT + c * 4);
        const float4 w2 = *(const float4*)(Wt + (f4 * 4 + 2) * F_OUT + c * 4);
        const float4 w3 = *(const float4*)(Wt + (f4 * 4 + 3) * F_OUT + c * 4);
        oacc.x += inq.x * w0.x; oacc.y += inq.x * w0.y; oacc.z += inq.x * w0.z; oacc.w += inq.x * w0.w;
        oacc.x += inq.y * w1.x; oacc.y += inq.y * w1.y; oacc.z += inq.y * w1.z; oacc.w += inq.y * w1.w;
        oacc.x += inq.z * w2.x; oacc.y += inq.z * w2.y; oacc.z += inq.z * w2.z; oacc.w += inq.z * w2.w;
        oacc.x += inq.w * w3.x; oacc.y += inq.w * w3.y; oacc.z += inq.w * w3.z; oacc.w += inq.w * w3.w;
    }

    *(float4*)(out + ((size_t)b * N_NODES + n) * F_OUT + c * 4) = oacc;
}

extern "C" void kernel_launch(void* const* d_in, const int* in_sizes, int n_in,
                              void* d_out, int out_size, void* d_ws, size_t ws_size,
                              hipStream_t stream) {
    const float* x  = (const float*)d_in[0];
    const float* Wl = (const float*)d_in[1];
    const float* bl = (const float*)d_in[2];
    const float* Wr = (const float*)d_in[3];
    const void*  ei = d_in[4];
    float* out = (float*)d_out;
    char* ws = (char*)d_ws;

    if (ws_size >= (size_t)WS2_TOTAL + 1024) {
        int*            flag = (int*)(ws + WS2_FLAG);
        unsigned short* Wt   = (unsigned short*)(ws + WS2_WT);
        int*            deg  = (int*)(ws + WS2_DEG);
        int*            rowp = (int*)(ws + WS2_ROW);
        int*            cur  = (int*)(ws + WS2_CUR);
        int*            col  = (int*)(ws + WS2_COL);
        uint2*          xh2  = (uint2*)(ws + WS2_XH);
        uint2*          z2   = (uint2*)(ws + WS2_Z);

        hipMemsetAsync(ws + WS2_DEG, 0, WS2_COL - WS2_DEG, stream);
        detect_i64_kernel<<<1, 256, 0, stream>>>(ei, flag);
        make_wt_bf16<<<128, 256, 0, stream>>>(Wl, Wr, Wt);
        hist_kernel<<<(N_EDGES + 255) / 256, 256, 0, stream>>>(ei, flag, deg);
        scan_kernel<<<1, 1024, 0, stream>>>(deg, rowp);
        scatter_kernel<<<(N_EDGES + 255) / 256, 256, 0, stream>>>(ei, flag, rowp, cur, col);
        convert_kernel<<<(NROWS * 32) / 256, 256, 0, stream>>>(x, xh2, z2);
        gather_bf16_kernel<<<N_NODES, 256, 0, stream>>>(xh2, rowp, col, z2);
        gemm_bf16_kernel<<<NROWS / 64, 256, 0, stream>>>(
            (const unsigned short*)z2, Wt, bl, out);
    } else {
        int*   flag      = (int*)(ws + WS_FLAG_OFF);
        float* Wt        = (float*)(ws + WS_WT_OFF);
        int*   deg       = (int*)(ws + WS_DEG_OFF);
        int*   row_start = (int*)(ws + WS_ROW_OFF);
        int*   cursor    = (int*)(ws + WS_CUR_OFF);
        int*   col       = (int*)(ws + WS_COL_OFF);

        hipMemsetAsync(d_ws, 0, WS_TOTAL, stream);
        detect_i64_kernel<<<1, 256, 0, stream>>>(ei, flag);
        transpose_w_kernel<<<(256 * 128) / 256, 256, 0, stream>>>(Wl, Wr, Wt);
        hist_kernel<<<(N_EDGES + 255) / 256, 256, 0, stream>>>(ei, flag, deg);
        scan_kernel<<<1, 1024, 0, stream>>>(deg, row_start);
        scatter_kernel<<<(N_EDGES + 255) / 256, 256, 0, stream>>>(ei, flag, row_start, cursor, col);
        sage_fused_kernel<<<N_NODES, 256, 0, stream>>>(x, bl, Wt, row_start, col, out);
    }
}